// Round 7
// baseline (4663.895 us; speedup 1.0000x reference)
//
#include <hip/hip_runtime.h>

// HierarchicalMultinomialRegression: channel-parallel fused kernel.
// One 8-lane group per row n; lane k owns output channel k (lane 7 = the
// zeros column of logits). Never materializes u (B,L,T,Km1).
//
// Round 7 fixes over round 6 (52.4us):
//  - launch_bounds(256,4): round 6's (256,8) capped VGPR at 32 (< ~45
//    needed) -> spill/throttle. 64-cap still permits 8 waves/SIMD.
//  - eps channel-slice batched upfront into e[20] regs (loads predicated
//    s<=t, group-uniform): one 20-deep MLP burst instead of 19 chained
//    1-step-prefetch exposures. Recurrence is pure-register, fully
//    unrolled, all static indexing.
//  - dropped the wave tmax reduce (divergent exec already runs wave-max).
//
// Inputs (setup_inputs dict order):
//  0: X (N,64) f32   1: beta (64,7) f32   2: raw_rho (7,7) f32
//  3: raw_chol (7,7,7) f32 (Km1,L,L)      4: eps (B,7,20,7) f32
//  5: batter_ids (N,) i32  6: league_ids  7: season_ids
// Output: logits (N,8) then eps_sample (N,7), concatenated flat, f32.

#define NF 64
#define LDIM 7
#define TDIM 20
#define KM1 7
#define BLOCK 256
#define RPB (BLOCK / 8)   // rows per block = 32

__device__ __forceinline__ float comp4(const float4& v, int c) {
    switch (c & 3) { case 0: return v.x; case 1: return v.y;
                     case 2: return v.z; default: return v.w; }
}

__global__ __launch_bounds__(BLOCK, 4) void hmr_kernel(
    const float* __restrict__ X,
    const float* __restrict__ beta,
    const float* __restrict__ raw_rho,
    const float* __restrict__ raw_chol,
    const float* __restrict__ eps,
    const int* __restrict__ batter_ids,
    const int* __restrict__ league_ids,
    const int* __restrict__ season_ids,
    float* __restrict__ out,
    int n_total)
{
    // small constants in LDS (padded so lane 7's reads stay in-bounds)
    __shared__ float s_beta[NF * KM1 + 8];   // beta[j][k]
    __shared__ float s_rho[56];              // tanh(raw_rho)[l][k]
    __shared__ float s_sd[56];               // scaling*diag [l][k]
    __shared__ float s_M[56];                // M[k][j] row-major

    const int tid = threadIdx.x;

    for (int i = tid; i < NF * KM1; i += BLOCK) s_beta[i] = beta[i];
    if (tid < 8) s_beta[NF * KM1 + tid] = 0.f;

    if (tid < LDIM * KM1) {
        const int l = tid / KM1, k = tid % KM1;
        const float r = tanhf(raw_rho[l * KM1 + k]);
        s_rho[tid] = r;
        s_sd[tid] = (1.0f / sqrtf(1.0f - r * r)) *
                    raw_chol[k * (LDIM * LDIM) + l * LDIM + l];
        const int k2 = l, j = k;             // reuse 7x7 index space for M
        float m = 0.f;
        #pragma unroll
        for (int i2 = 0; i2 < LDIM; ++i2)
            m += raw_chol[k2 * (LDIM * LDIM) + i2 * LDIM + j];
        s_M[k2 * KM1 + j] = m;
    } else if (tid < 56) {
        s_rho[tid] = 0.f; s_sd[tid] = 0.f; s_M[tid] = 0.f;
    }
    __syncthreads();

    const int r = tid >> 3;          // row within block
    const int klane = tid & 7;       // channel (7 = zeros column)
    const int k_ld = (klane < 6) ? klane : 6;   // clamp for safe loads
    int n = blockIdx.x * RPB + r;
    const bool valid = (n < n_total);
    if (!valid) n = n_total - 1;     // clamp loads; stores predicated below

    const int b = batter_ids[n];
    const int l = league_ids[n];
    const int t = season_ids[n];

    // ---- fixed effects: acc = sum_j X[n,j] * beta[j,klane] ----
    // (done first: keeps peak live-register state low)
    float acc = 0.f;
    const float4* __restrict__ xrow =
        reinterpret_cast<const float4*>(X + (long)n * NF);
    #pragma unroll 2
    for (int j4 = 0; j4 < NF / 4; ++j4) {
        const float4 x = xrow[j4];
        #pragma unroll
        for (int jj = 0; jj < 4; ++jj)
            acc = fmaf(comp4(x, jj), s_beta[(j4 * 4 + jj) * KM1 + klane], acc);
    }

    // ---- per-lane constants ----
    float Mcol[KM1];
    #pragma unroll
    for (int kk = 0; kk < KM1; ++kk) Mcol[kk] = s_M[kk * KM1 + klane];
    const float rho = s_rho[l * KM1 + klane];
    const float sd  = s_sd[l * KM1 + klane];

    // ---- batch-load own eps channel slice: 20-deep MLP, one exposure ----
    const float* __restrict__ erow = eps + ((long)b * LDIM + l) * (TDIM * KM1);
    float e[TDIM];
    e[0] = erow[k_ld];
    #pragma unroll
    for (int s = 1; s < TDIM; ++s) {
        e[s] = 0.f;
        if (s <= t) e[s] = erow[s * KM1 + k_ld];   // group-uniform predicate
    }

    // ---- AR(1) recurrence: pure-register, fully unrolled ----
    float u = sd * e[0];
    float last_e = e[0];
    #pragma unroll
    for (int s = 1; s < TDIM; ++s) {
        if (s <= t) {                 // group-uniform; wave runs its max t
            float nz = 0.f;
            #pragma unroll
            for (int kk = 0; kk < KM1; ++kk)
                nz = fmaf(Mcol[kk], __shfl(e[s], kk, 8), nz);
            u = fmaf(rho, u, nz);
            if (s == t) last_e = e[s];
        }
    }

    // ---- coalesced writes, no staging ----
    if (valid) {
        // wave covers 64 consecutive dwords of the logits region (256B)
        const int col = (klane == 7) ? 0 : klane + 1;
        out[(long)n * 8 + col] = (klane == 7) ? 0.f : (acc + u);
        // eps_sample: contiguous fully-covered 224B span per wave
        if (klane < KM1)
            out[(long)n_total * 8 + (long)n * KM1 + klane] = last_e;
    }
}

extern "C" void kernel_launch(void* const* d_in, const int* in_sizes, int n_in,
                              void* d_out, int out_size, void* d_ws, size_t ws_size,
                              hipStream_t stream)
{
    const float* X        = (const float*)d_in[0];
    const float* beta     = (const float*)d_in[1];
    const float* raw_rho  = (const float*)d_in[2];
    const float* raw_chol = (const float*)d_in[3];
    const float* eps      = (const float*)d_in[4];
    const int* batter_ids = (const int*)d_in[5];
    const int* league_ids = (const int*)d_in[6];
    const int* season_ids = (const int*)d_in[7];
    float* out = (float*)d_out;

    const int n_total = in_sizes[5];  // N = 200000
    const int grid = (n_total + RPB - 1) / RPB;

    hmr_kernel<<<grid, BLOCK, 0, stream>>>(X, beta, raw_rho, raw_chol, eps,
                                           batter_ids, league_ids, season_ids,
                                           out, n_total);
}

// Round 8
// 51.391 us; speedup vs baseline: 90.7523x; 90.7523x over previous
//
#include <hip/hip_runtime.h>

// HierarchicalMultinomialRegression: channel-parallel fused kernel.
// One 8-lane group per row n; lane k owns output channel k (lane 7 = the
// zeros column of logits). Never materializes u (B,L,T,Km1).
//
// Round 8 = round-6 structure with the register-cap mistakes removed:
//  - __launch_bounds__(256) ONLY. Rounds 2/6/7 proved any min-waves arg
//    that clamps below natural need (~50 regs here) causes scratch-spill
//    catastrophe (r7: 22GB scratch writes, 4664us). Natural ~50 regs ->
//    8 waves/SIMD tier anyway.
//  - streaming 1-ahead eps prefetch (bounded state; no e[20] batch).
//  - divergent per-group `s<=t` loop (groups are t-uniform: all 8 lanes
//    share n). No wave tmax reduce needed.
//
// Inputs (setup_inputs dict order):
//  0: X (N,64) f32   1: beta (64,7) f32   2: raw_rho (7,7) f32
//  3: raw_chol (7,7,7) f32 (Km1,L,L)      4: eps (B,7,20,7) f32
//  5: batter_ids (N,) i32  6: league_ids  7: season_ids
// Output: logits (N,8) then eps_sample (N,7), concatenated flat, f32.

#define NF 64
#define LDIM 7
#define TDIM 20
#define KM1 7
#define BLOCK 256
#define RPB (BLOCK / 8)   // rows per block = 32

__device__ __forceinline__ float comp4(const float4& v, int c) {
    switch (c & 3) { case 0: return v.x; case 1: return v.y;
                     case 2: return v.z; default: return v.w; }
}

__global__ __launch_bounds__(BLOCK) void hmr_kernel(
    const float* __restrict__ X,
    const float* __restrict__ beta,
    const float* __restrict__ raw_rho,
    const float* __restrict__ raw_chol,
    const float* __restrict__ eps,
    const int* __restrict__ batter_ids,
    const int* __restrict__ league_ids,
    const int* __restrict__ season_ids,
    float* __restrict__ out,
    int n_total)
{
    // small constants in LDS (padded so lane 7's reads stay in-bounds)
    __shared__ float s_beta[NF * KM1 + 8];   // beta[j][k]
    __shared__ float s_rho[56];              // tanh(raw_rho)[l][k]
    __shared__ float s_sd[56];               // scaling*diag [l][k]
    __shared__ float s_M[56];                // M[k][j] row-major

    const int tid = threadIdx.x;

    for (int i = tid; i < NF * KM1; i += BLOCK) s_beta[i] = beta[i];
    if (tid < 8) s_beta[NF * KM1 + tid] = 0.f;

    if (tid < LDIM * KM1) {
        const int l = tid / KM1, k = tid % KM1;
        const float r = tanhf(raw_rho[l * KM1 + k]);
        s_rho[tid] = r;
        s_sd[tid] = (1.0f / sqrtf(1.0f - r * r)) *
                    raw_chol[k * (LDIM * LDIM) + l * LDIM + l];
        const int k2 = l, j = k;             // reuse 7x7 index space for M
        float m = 0.f;
        #pragma unroll
        for (int i2 = 0; i2 < LDIM; ++i2)
            m += raw_chol[k2 * (LDIM * LDIM) + i2 * LDIM + j];
        s_M[k2 * KM1 + j] = m;
    } else if (tid < 56) {
        s_rho[tid] = 0.f; s_sd[tid] = 0.f; s_M[tid] = 0.f;
    }
    __syncthreads();

    const int r = tid >> 3;          // row within block
    const int klane = tid & 7;       // channel (7 = zeros column)
    const int k_ld = (klane < 6) ? klane : 6;   // clamp for safe loads
    int n = blockIdx.x * RPB + r;
    const bool valid = (n < n_total);
    if (!valid) n = n_total - 1;     // clamp loads; stores predicated below

    const int b = batter_ids[n];
    const int l = league_ids[n];
    const int t = season_ids[n];

    // ---- fixed effects: acc = sum_j X[n,j] * beta[j,klane] ----
    float acc = 0.f;
    const float4* __restrict__ xrow =
        reinterpret_cast<const float4*>(X + (long)n * NF);
    #pragma unroll 4
    for (int j4 = 0; j4 < NF / 4; ++j4) {
        const float4 x = xrow[j4];
        #pragma unroll
        for (int jj = 0; jj < 4; ++jj)
            acc = fmaf(comp4(x, jj), s_beta[(j4 * 4 + jj) * KM1 + klane], acc);
    }

    // ---- per-lane constants ----
    float Mcol[KM1];
    #pragma unroll
    for (int kk = 0; kk < KM1; ++kk) Mcol[kk] = s_M[kk * KM1 + klane];
    const float rho = s_rho[l * KM1 + klane];
    const float sd  = s_sd[l * KM1 + klane];

    // ---- AR(1) recurrence, channel-parallel, streaming 1-ahead ----
    const float* __restrict__ erow = eps + ((long)b * LDIM + l) * (TDIM * KM1);

    const float e0 = erow[k_ld];
    float u = sd * e0;
    float last_e = e0;

    if (t > 0) {
        float ecur = erow[KM1 + k_ld];           // step 1, own channel
        for (int s = 1; s <= t; ++s) {           // group-uniform bound
            const int snext = (s + 1 < TDIM) ? s + 1 : TDIM - 1;
            const float enext = erow[snext * KM1 + k_ld];  // prefetch
            float nz = 0.f;
            #pragma unroll
            for (int kk = 0; kk < KM1; ++kk)
                nz = fmaf(Mcol[kk], __shfl(ecur, kk, 8), nz);
            u = fmaf(rho, u, nz);
            last_e = ecur;                       // holds e[t] at loop exit
            ecur = enext;
        }
    }

    // ---- coalesced writes, no staging ----
    if (valid) {
        // wave covers 64 consecutive dwords (256B) of the logits region
        const int col = (klane == 7) ? 0 : klane + 1;
        out[(long)n * 8 + col] = (klane == 7) ? 0.f : (acc + u);
        // eps_sample: wave covers a contiguous 224B span, fully written
        if (klane < KM1)
            out[(long)n_total * 8 + (long)n * KM1 + klane] = last_e;
    }
}

extern "C" void kernel_launch(void* const* d_in, const int* in_sizes, int n_in,
                              void* d_out, int out_size, void* d_ws, size_t ws_size,
                              hipStream_t stream)
{
    const float* X        = (const float*)d_in[0];
    const float* beta     = (const float*)d_in[1];
    const float* raw_rho  = (const float*)d_in[2];
    const float* raw_chol = (const float*)d_in[3];
    const float* eps      = (const float*)d_in[4];
    const int* batter_ids = (const int*)d_in[5];
    const int* league_ids = (const int*)d_in[6];
    const int* season_ids = (const int*)d_in[7];
    float* out = (float*)d_out;

    const int n_total = in_sizes[5];  // N = 200000
    const int grid = (n_total + RPB - 1) / RPB;

    hmr_kernel<<<grid, BLOCK, 0, stream>>>(X, beta, raw_rho, raw_chol, eps,
                                           batter_ids, league_ids, season_ids,
                                           out, n_total);
}

// Round 9
// 46.659 us; speedup vs baseline: 99.9560x; 1.1014x over previous
//
#include <hip/hip_runtime.h>

// HierarchicalMultinomialRegression: channel-parallel fused kernel with the
// AR(1) recurrence algebraically reformulated to eliminate in-loop shuffles.
//
// u_t[j] = rho_j^t * (sd_j * e0[j]) + sum_k M[k][j] * w_j[k],
//   w_j[k] = sum_{s=1..t} rho_j^{t-s} * e_s[k]   (per-lane scalar AR chains)
//
// Lane k of each 8-lane group owns channel k: loads e_s[k] (1 scalar/step)
// and updates w[j] for all j (7 FMA/step, NO LDS ops). The M^T mix happens
// ONCE after the loop: p[j] = M[k][j]*w[j], 8-lane butterfly reduce
// (21 shfl_xor width-8), then a 7-deep cndmask select picks own channel.
// Round 8 was LDS-pipe bound (~850 cy/wave: 64 beta ds_read_b32 + 119
// in-loop bpermutes); this cuts LDS to ~280 cy/wave:
//  - in-loop shuffles 119 -> 0 (one-time 21)
//  - beta staged TRANSPOSED+padded [8][68]: lane k reads its column as 16
//    conflict-free broadcast ds_read_b128 (stride 68 floats -> lanes hit
//    disjoint 4-bank windows) instead of 64 scalar b32.
// No launch_bounds min-waves arg (rounds 2/6/7: any cap below natural need
// spills catastrophically). Natural need ~55-70 VGPR.
//
// Inputs (setup_inputs dict order):
//  0: X (N,64) f32   1: beta (64,7) f32   2: raw_rho (7,7) f32
//  3: raw_chol (7,7,7) f32 (Km1,L,L)      4: eps (B,7,20,7) f32
//  5: batter_ids (N,) i32  6: league_ids  7: season_ids
// Output: logits (N,8) then eps_sample (N,7), concatenated flat, f32.

#define NF 64
#define LDIM 7
#define TDIM 20
#define KM1 7
#define BLOCK 256
#define RPB (BLOCK / 8)   // rows per block = 32
#define BPAD 68           // betaT row stride (floats): 68k mod 32 = 4k -> spread

__global__ __launch_bounds__(BLOCK) void hmr_kernel(
    const float* __restrict__ X,
    const float* __restrict__ beta,
    const float* __restrict__ raw_rho,
    const float* __restrict__ raw_chol,
    const float* __restrict__ eps,
    const int* __restrict__ batter_ids,
    const int* __restrict__ league_ids,
    const int* __restrict__ season_ids,
    float* __restrict__ out,
    int n_total)
{
    __shared__ __align__(16) float s_betaT[8][BPAD];  // betaT[k][j] = beta[j][k]
    __shared__ float s_rho[LDIM * 8];    // rho[l][j], row stride 8
    __shared__ float s_sd[LDIM * 8];     // sd[l][k],  row stride 8
    __shared__ float s_M[8 * 8];         // M[k][j], row stride 8, row 7 = 0

    const int tid = threadIdx.x;

    // stage beta transposed
    for (int i = tid; i < NF * KM1; i += BLOCK) {
        const int j = i / KM1, k = i - j * KM1;   // beta is [j][k] row-major
        s_betaT[k][j] = beta[i];
    }
    // stage M (padded, row 7 zeroed) and rho/sd tables
    if (tid < 64) {
        const int a = tid >> 3, c = tid & 7;
        float m = 0.f;
        if (a < KM1 && c < KM1) {
            #pragma unroll
            for (int i2 = 0; i2 < LDIM; ++i2)
                m += raw_chol[a * 49 + i2 * 7 + c];   // M[k=a][j=c]
        }
        s_M[tid] = m;
        if (a < LDIM) {
            float r = 0.f, sdv = 0.f;
            if (c < KM1) {
                r = tanhf(raw_rho[a * KM1 + c]);
                sdv = (1.0f / sqrtf(1.0f - r * r)) * raw_chol[c * 49 + a * 7 + a];
            }
            s_rho[a * 8 + c] = r;
            s_sd[a * 8 + c] = sdv;
        }
    }
    __syncthreads();

    const int r = tid >> 3;          // row within block
    const int klane = tid & 7;       // channel (7 = zeros column of logits)
    const int k_ld = (klane < 6) ? klane : 6;   // clamp for safe channel loads
    int n = blockIdx.x * RPB + r;
    const bool valid = (n < n_total);
    if (!valid) n = n_total - 1;     // clamp loads; stores predicated below

    const int b = batter_ids[n];
    const int l = league_ids[n];
    const int t = season_ids[n];

    // ---- fixed effects: acc = sum_j X[n,j] * beta[j,klane] ----
    // betaT row k_ld: 16 broadcast ds_read_b128, conflict-free (stride 68)
    float acc = 0.f;
    const float4* __restrict__ xrow =
        reinterpret_cast<const float4*>(X + (long)n * NF);
    const float4* __restrict__ brow =
        reinterpret_cast<const float4*>(&s_betaT[k_ld][0]);
    #pragma unroll 4
    for (int j4 = 0; j4 < NF / 4; ++j4) {
        const float4 x = xrow[j4];
        const float4 bb = brow[j4];
        acc = fmaf(x.x, bb.x, fmaf(x.y, bb.y,
              fmaf(x.z, bb.z, fmaf(x.w, bb.w, acc))));
    }

    // ---- per-lane constants ----
    float rho_all[KM1], Mrow[KM1];
    #pragma unroll
    for (int j = 0; j < KM1; ++j) rho_all[j] = s_rho[l * 8 + j];
    #pragma unroll
    for (int j = 0; j < KM1; ++j) Mrow[j] = s_M[klane * 8 + j];  // lane7: zeros
    const float sd      = s_sd[l * 8 + k_ld];
    const float rho_own = s_rho[l * 8 + k_ld];

    // ---- AR chains: w[j] = sum_s rho_j^{t-s} e_s[klane], no LDS in loop ----
    const float* __restrict__ erow = eps + ((long)b * LDIM + l) * (TDIM * KM1);
    const float e0 = erow[k_ld];

    float w[KM1];
    #pragma unroll
    for (int j = 0; j < KM1; ++j) w[j] = 0.f;
    float rp = 1.f;          // rho_own^s tracker
    float last_e = e0;

    for (int s = 1; s <= t; ++s) {          // t is group-uniform
        const float e = erow[s * KM1 + k_ld];
        #pragma unroll
        for (int j = 0; j < KM1; ++j) w[j] = fmaf(rho_all[j], w[j], e);
        rp *= rho_own;
        last_e = e;
    }

    // ---- one-time M^T mix: p[j] = M[klane][j]*w[j], butterfly over group ----
    float v[KM1];
    #pragma unroll
    for (int j = 0; j < KM1; ++j) v[j] = Mrow[j] * w[j];
    #pragma unroll
    for (int j = 0; j < KM1; ++j) {
        v[j] += __shfl_xor(v[j], 1, 8);
        v[j] += __shfl_xor(v[j], 2, 8);
        v[j] += __shfl_xor(v[j], 4, 8);
    }
    // select own channel (static indices -> cndmask chain, no scratch)
    float nzt = v[0];
    #pragma unroll
    for (int j = 1; j < KM1; ++j) nzt = (klane == j) ? v[j] : nzt;

    const float u = fmaf(rp * sd, e0, nzt);  // rho^t*sd*e0 + sum_k M[k][j]w

    // ---- coalesced writes, no staging ----
    if (valid) {
        // wave covers 64 consecutive dwords (256B) of the logits region
        const int col = (klane == 7) ? 0 : klane + 1;
        out[(long)n * 8 + col] = (klane == 7) ? 0.f : (acc + u);
        // eps_sample: wave covers a contiguous 224B span, fully written
        if (klane < KM1)
            out[(long)n_total * 8 + (long)n * KM1 + klane] = last_e;
    }
}

extern "C" void kernel_launch(void* const* d_in, const int* in_sizes, int n_in,
                              void* d_out, int out_size, void* d_ws, size_t ws_size,
                              hipStream_t stream)
{
    const float* X        = (const float*)d_in[0];
    const float* beta     = (const float*)d_in[1];
    const float* raw_rho  = (const float*)d_in[2];
    const float* raw_chol = (const float*)d_in[3];
    const float* eps      = (const float*)d_in[4];
    const int* batter_ids = (const int*)d_in[5];
    const int* league_ids = (const int*)d_in[6];
    const int* season_ids = (const int*)d_in[7];
    float* out = (float*)d_out;

    const int n_total = in_sizes[5];  // N = 200000
    const int grid = (n_total + RPB - 1) / RPB;

    hmr_kernel<<<grid, BLOCK, 0, stream>>>(X, beta, raw_rho, raw_chol, eps,
                                           batter_ids, league_ids, season_ids,
                                           out, n_total);
}

// Round 11
// 35.933 us; speedup vs baseline: 129.7929x; 1.2985x over previous
//
#include <hip/hip_runtime.h>

// HierarchicalMultinomialRegression: channel-parallel fused kernel, round 11.
// = round 10 with the time-weight fold fixed.
//
// u_t[j] = rho_j^t sd_j e0[j] + sum_{s=1..t} rho_j^{t-s} nz_s[j],
//   nz_s[j] = sum_k eps_s[k] * M[k][j].
// Lane p of each 8-lane group owns steps {p+1, p+9, p+17} and loads each
// owned step's FULL 7-float row once -> each eps cacheline touched ~once
// (round 3/9 step-serial loads re-touched each line ~10x; theory: that
// L3->L2 re-fetch traffic (~330MB @128B lines) is the shared ~47us wall).
// M held in 49 SGPRs (readfirstlane; v_fma takes one SGPR operand).
//
// FOLD FIX vs round 10: forward fold (i=0..2): q = r8*q + nz_s gives nz at
// owned step s=p+1+8i the coefficient rho^{8(imax-i)}; then scale by
// rho^{(t-p-1)&7} (= rho^{t-s_max}, exponent always <8 since t<=19) for a
// total of rho^{t-s}. Round 10 folded backwards -> rho^{t-p-1+8i}, absmax 69.
// Then one 21-shfl_xor butterfly + static cndmask select. Zero LDS ops in
// the step loop; no runtime-indexed reg arrays; no launch_bounds min-waves
// cap (spill lessons r2/r6/r7).
//
// Inputs: 0:X(N,64) 1:beta(64,7) 2:raw_rho(7,7) 3:raw_chol(7,7,7)
//         4:eps(B,7,20,7) 5:batter_ids 6:league_ids 7:season_ids
// Output: logits (N,8) then eps_sample (N,7), concat flat, f32.

#define NF 64
#define LDIM 7
#define TDIM 20
#define KM1 7
#define BLOCK 256
#define RPB (BLOCK / 8)   // rows per block = 32
#define BPAD 68           // betaT row stride (floats)

__device__ __forceinline__ float rfl(float x) {
    return __int_as_float(__builtin_amdgcn_readfirstlane(__float_as_int(x)));
}

__global__ __launch_bounds__(BLOCK) void hmr_kernel(
    const float* __restrict__ X,
    const float* __restrict__ beta,
    const float* __restrict__ raw_rho,
    const float* __restrict__ raw_chol,
    const float* __restrict__ eps,
    const int* __restrict__ batter_ids,
    const int* __restrict__ league_ids,
    const int* __restrict__ season_ids,
    float* __restrict__ out,
    int n_total)
{
    __shared__ __align__(16) float s_betaT[8][BPAD];  // betaT[k][j] = beta[j][k]
    __shared__ float s_rho[LDIM * 8];    // rho[l][k]
    __shared__ float s_sd[LDIM * 8];     // sd[l][k]
    __shared__ float s_M[64];            // M[k][j] stride 8, padded zero

    const int tid = threadIdx.x;

    for (int i = tid; i < NF * KM1; i += BLOCK) {
        const int j = i / KM1, k = i - j * KM1;
        s_betaT[k][j] = beta[i];
    }
    if (tid < 64) {
        const int a = tid >> 3, c = tid & 7;
        float m = 0.f;
        if (a < KM1 && c < KM1) {
            #pragma unroll
            for (int i2 = 0; i2 < LDIM; ++i2)
                m += raw_chol[a * 49 + i2 * 7 + c];   // M[k=a][j=c]
        }
        s_M[tid] = m;
        if (a < LDIM) {
            float r = 0.f, sdv = 0.f;
            if (c < KM1) {
                r = tanhf(raw_rho[a * KM1 + c]);
                sdv = (1.0f / sqrtf(1.0f - r * r)) * raw_chol[c * 49 + a * 7 + a];
            }
            s_rho[a * 8 + c] = r;
            s_sd[a * 8 + c] = sdv;
        }
    }
    __syncthreads();

    const int r = tid >> 3;          // row within block
    const int p = tid & 7;           // lane-in-group: channel owner AND step owner
    const int k_ld = (p < 6) ? p : 6;
    int n = blockIdx.x * RPB + r;
    const bool valid = (n < n_total);
    if (!valid) n = n_total - 1;

    const int b = batter_ids[n];
    const int l = league_ids[n];
    const int t = season_ids[n];

    // ---- fixed effects: acc = sum_j X[n,j] * beta[j, p] ----
    float acc = 0.f;
    {
        const float4* __restrict__ xrow =
            reinterpret_cast<const float4*>(X + (long)n * NF);
        const float4* __restrict__ brow =
            reinterpret_cast<const float4*>(&s_betaT[k_ld][0]);
        #pragma unroll 4
        for (int j4 = 0; j4 < NF / 4; ++j4) {
            const float4 x = xrow[j4];
            const float4 bb = brow[j4];
            acc = fmaf(x.x, bb.x, fmaf(x.y, bb.y,
                  fmaf(x.z, bb.z, fmaf(x.w, bb.w, acc))));
        }
    }

    // ---- hoist wave-uniform M into SGPRs ----
    float mm[KM1 * KM1];
    #pragma unroll
    for (int k = 0; k < KM1; ++k)
        #pragma unroll
        for (int j = 0; j < KM1; ++j)
            mm[k * KM1 + j] = rfl(s_M[k * 8 + j]);

    // ---- per-group rho vector + rho^8 ----
    float rho_all[KM1], r8[KM1];
    #pragma unroll
    for (int j = 0; j < KM1; ++j) {
        rho_all[j] = s_rho[l * 8 + j];
        const float r2 = rho_all[j] * rho_all[j];
        const float r4 = r2 * r2;
        r8[j] = r4 * r4;
    }

    const float* __restrict__ erow = eps + ((long)b * LDIM + l) * (TDIM * KM1);

    // ---- owned steps s = p+1+8i, FORWARD fold (earliest first) ----
    // After the fold, nz at owned step i carries r8^{imax-i}; the residual
    // scale rho^{t - s_max} = rho^{(t-p-1)&7} is applied below.
    float q[KM1];
    #pragma unroll
    for (int j = 0; j < KM1; ++j) q[j] = 0.f;

    #pragma unroll
    for (int i = 0; i < 3; ++i) {
        const int s = p + 1 + 8 * i;
        if (s <= t) {                      // t<=19 so s<TDIM guaranteed
            float e[KM1];
            #pragma unroll
            for (int k = 0; k < KM1; ++k) e[k] = erow[s * KM1 + k];
            #pragma unroll
            for (int j = 0; j < KM1; ++j) {
                float nz = 0.f;
                #pragma unroll
                for (int k = 0; k < KM1; ++k)
                    nz = fmaf(e[k], mm[k * KM1 + j], nz);  // SGPR operand
                q[j] = fmaf(r8[j], q[j], nz);
            }
        }
    }

    // ---- scale by rho_j^((t-p-1)&7)  (q==0 when t<p+1, so &7 is safe) ----
    {
        const int m = (t - p - 1) & 7;
        float bs[KM1];
        #pragma unroll
        for (int j = 0; j < KM1; ++j) bs[j] = rho_all[j];
        #pragma unroll
        for (int bit = 0; bit < 3; ++bit) {
            const bool on = ((m >> bit) & 1) != 0;
            #pragma unroll
            for (int j = 0; j < KM1; ++j) {
                q[j] *= on ? bs[j] : 1.f;
                bs[j] *= bs[j];
            }
        }
    }

    // ---- butterfly-sum q over the 8-lane group ----
    #pragma unroll
    for (int j = 0; j < KM1; ++j) {
        q[j] += __shfl_xor(q[j], 1, 8);
        q[j] += __shfl_xor(q[j], 2, 8);
        q[j] += __shfl_xor(q[j], 4, 8);
    }
    // select own channel (static indices -> cndmask chain)
    float nzt = q[0];
    #pragma unroll
    for (int j = 1; j < KM1; ++j) nzt = (p == j) ? q[j] : nzt;

    // ---- e0 term: rho_own^t * sd * e0 ----
    const float e0 = erow[k_ld];
    const float sd = s_sd[l * 8 + k_ld];
    const float rho_own = s_rho[l * 8 + k_ld];
    float pwt = 1.f;
    {
        float bo = rho_own;
        #pragma unroll
        for (int bit = 0; bit < 5; ++bit) {
            pwt *= (((t >> bit) & 1) != 0) ? bo : 1.f;
            bo *= bo;
        }
    }
    const float u = fmaf(pwt * sd, e0, nzt);
    const float last_e = erow[t * KM1 + k_ld];

    // ---- coalesced writes, no staging ----
    if (valid) {
        const int col = (p == 7) ? 0 : p + 1;
        out[(long)n * 8 + col] = (p == 7) ? 0.f : (acc + u);
        if (p < KM1)
            out[(long)n_total * 8 + (long)n * KM1 + p] = last_e;
    }
}

extern "C" void kernel_launch(void* const* d_in, const int* in_sizes, int n_in,
                              void* d_out, int out_size, void* d_ws, size_t ws_size,
                              hipStream_t stream)
{
    const float* X        = (const float*)d_in[0];
    const float* beta     = (const float*)d_in[1];
    const float* raw_rho  = (const float*)d_in[2];
    const float* raw_chol = (const float*)d_in[3];
    const float* eps      = (const float*)d_in[4];
    const int* batter_ids = (const int*)d_in[5];
    const int* league_ids = (const int*)d_in[6];
    const int* season_ids = (const int*)d_in[7];
    float* out = (float*)d_out;

    const int n_total = in_sizes[5];  // N = 200000
    const int grid = (n_total + RPB - 1) / RPB;

    hmr_kernel<<<grid, BLOCK, 0, stream>>>(X, beta, raw_rho, raw_chol, eps,
                                           batter_ids, league_ids, season_ids,
                                           out, n_total);
}